// Round 8
// baseline (139.789 us; speedup 1.0000x reference)
//
#include <hip/hip_runtime.h>
#include <cstdint>

#define N_ 4
#define L_ 8192
#define S_ 8192
#define H_ 8
#define D_ 64
#define E_ 64
#define HD_ 512       // H_*D_ row stride in floats
#define NH_ 32        // N_*H_
#define EPS_ 1e-6f
#define RS_ 68        // padded LDS row stride (floats) for p2 Q tile
#define TS_ 32        // s-rows per tile (p1)

__device__ __forceinline__ float elu1(float x) {
  return x > 0.0f ? x + 1.0f : __expf(x);
}

__device__ __forceinline__ void gl_lds_16B(const void* g, void* l) {
  __builtin_amdgcn_global_load_lds(
      (const __attribute__((address_space(1))) unsigned int*)g,
      (__attribute__((address_space(3))) unsigned int*)l, 16, 0, 0);
}

// cross-lane xor-reductions on the VALU (permlane*_swap), not the LDS pipe.
__device__ __forceinline__ float red16(float x) {
#if __has_builtin(__builtin_amdgcn_permlane16_swap)
  unsigned u = __float_as_uint(x);
  auto r = __builtin_amdgcn_permlane16_swap(u, u, false, false);
  return __uint_as_float((unsigned)r[0]) + __uint_as_float((unsigned)r[1]);
#else
  return x + __shfl_xor(x, 16, 64);
#endif
}
__device__ __forceinline__ float red32(float x) {
#if __has_builtin(__builtin_amdgcn_permlane32_swap)
  unsigned u = __float_as_uint(x);
  auto r = __builtin_amdgcn_permlane32_swap(u, u, false, false);
  return __uint_as_float((unsigned)r[0]) + __uint_as_float((unsigned)r[1]);
#else
  return x + __shfl_xor(x, 32, 64);
#endif
}

// ---------------- phase 1: partial KV/Ksum per block (NO atomics) -----------
// grid (C=32, H, N), block 512 (8 waves), LDS 40960 B -> 4 blocks/CU, 1 round.
// Counted-wait pipeline, one barrier per tile:
//   A: elu+stage K(t) from kreg            (auto-wait = vmcnt(1): K issued
//      BEFORE V at B(t-1), so V(t) stays in flight here)
//   B: issue K(t+1) [regs] THEN V(t+1) [gl_lds]  (order pinned: K older)
//   W: sched_barrier; lgkmcnt(0); s_barrier; vmcnt(2) (V(t) landed, K/V(t+1)
//      in flight; last tile: vmcnt(0)); sched_barrier
//   C: compute tile t.
// fk ping-pong + V 3-deep tolerate the 1-iteration max barrier skew.
__global__ __launch_bounds__(512, 8) void p1_kv(const float* __restrict__ keys,
                                                const float* __restrict__ values,
                                                float* __restrict__ pkv,
                                                float* __restrict__ pks,
                                                int tiles) {
  const int chunk = blockIdx.x, h = blockIdx.y, n = blockIdx.z;
  const int tid = threadIdx.x;
  const int w = tid >> 6, lane = tid & 63;
  const int sg = lane >> 4, eg = lane & 15;
  __shared__ float fk_lds[2][TS_ * 64];     // 16384 B, ping-pong, XOR-swizzled
  __shared__ float v_lds[3][TS_ * 64];      // 24576 B, 3-deep gl_lds dest

  const int srow = tid >> 4;                // 0..31 (also V src row)
  const int scol = (tid & 15) * 4;          // (also V src col)
  const int scolw = scol ^ ((srow & 3) << 3);   // swizzled fk write col
  const int dswz  = (w * 8) ^ (sg << 3);        // swizzled fk read base

  const float* Kb = keys   + (size_t)n * S_ * HD_ + h * D_;
  const float* Vb = values + (size_t)n * S_ * HD_ + h * D_;

  float acc[8][4];
  #pragma unroll
  for (int i = 0; i < 8; ++i)
    #pragma unroll
    for (int j = 0; j < 4; ++j) acc[i][j] = 0.0f;
  float4 kss = make_float4(0.f, 0.f, 0.f, 0.f);

  const int sbase = chunk * tiles * TS_;
  unsigned koff = (unsigned)((sbase + srow) * HD_ + scol);  // 32-bit offsets

  // prologue: K(0) first (older), then V(0)
  float4 kreg = *(const float4*)(Kb + koff);
  __builtin_amdgcn_sched_barrier(0);
  gl_lds_16B(Vb + koff, &v_lds[0][w * 256]);

  int vr = 0, vw = 1;   // V read/write buffer indices (mod 3)
  #pragma unroll 1
  for (int t = 0; t < tiles; ++t) {
    // ---- A: stage K tile t ------------------------------------------------
    {
      float4 f;
      f.x = elu1(kreg.x); f.y = elu1(kreg.y); f.z = elu1(kreg.z); f.w = elu1(kreg.w);
      kss.x += f.x; kss.y += f.y; kss.z += f.z; kss.w += f.w;
      *(float4*)&fk_lds[t & 1][srow * 64 + scolw] = f;
    }
    // ---- B: issue K(t+1) THEN V(t+1) (K must be the older op) -------------
    if (t + 1 < tiles) {
      koff += TS_ * HD_;
      kreg = *(const float4*)(Kb + koff);
      __builtin_amdgcn_sched_barrier(0);    // pin order: K before gl_lds V
      gl_lds_16B(Vb + koff, &v_lds[vw][w * 256]);
    }
    // ---- W: barrier with counted vmcnt -------------------------------------
    __builtin_amdgcn_sched_barrier(0);      // ds_write stays above
    asm volatile("s_waitcnt lgkmcnt(0)");
    __builtin_amdgcn_s_barrier();
    if (t + 1 < tiles) asm volatile("s_waitcnt vmcnt(2)");
    else               asm volatile("s_waitcnt vmcnt(0)");
    __builtin_amdgcn_sched_barrier(0);      // compute stays below
    // ---- C: compute tile t -------------------------------------------------
    const float* vb = &v_lds[vr][0];
    const float* fb = &fk_lds[t & 1][0];
    #pragma unroll
    for (int g4 = 0; g4 < 8; ++g4) {
      const int s = g4 * 4 + sg;
      float4 vv = *(const float4*)&vb[s * 64 + eg * 4];
      const float* fr = &fb[s * 64 + dswz];
      float4 k0 = *(const float4*)(fr + 0);
      float4 k1 = *(const float4*)(fr + 4);
      #define ACCROW(di, kc)                          \
        acc[di][0] = fmaf(kc, vv.x, acc[di][0]);      \
        acc[di][1] = fmaf(kc, vv.y, acc[di][1]);      \
        acc[di][2] = fmaf(kc, vv.z, acc[di][2]);      \
        acc[di][3] = fmaf(kc, vv.w, acc[di][3]);
      ACCROW(0, k0.x) ACCROW(1, k0.y) ACCROW(2, k0.z) ACCROW(3, k0.w)
      ACCROW(4, k1.x) ACCROW(5, k1.y) ACCROW(6, k1.z) ACCROW(7, k1.w)
      #undef ACCROW
    }
    vr = (vr == 2) ? 0 : vr + 1;
    vw = (vw == 2) ? 0 : vw + 1;
  }

  // butterfly-reduce the 4-way s split (VALU permlanes)
  #pragma unroll
  for (int i = 0; i < 8; ++i)
    #pragma unroll
    for (int j = 0; j < 4; ++j)
      acc[i][j] = red32(red16(acc[i][j]));

  // plain coalesced stores of the block's partial 64x64 tile
  float* pkvb = pkv + ((size_t)chunk * NH_ + (size_t)(n * H_ + h)) * (D_ * E_);
  if (sg == 0) {
    #pragma unroll
    for (int i = 0; i < 8; ++i) {
      float4 o = make_float4(acc[i][0], acc[i][1], acc[i][2], acc[i][3]);
      *(float4*)&pkvb[(w * 8 + i) * E_ + eg * 4] = o;
    }
  }

  // partial Ksum: block-reduce in fk_lds[0]
  __syncthreads();
  *(float4*)&fk_lds[0][srow * 64 + scol] = kss;
  __syncthreads();
  if (tid < 64) {
    float s = 0.f;
    #pragma unroll
    for (int r = 0; r < 32; ++r) s += fk_lds[0][r * 64 + tid];
    pks[((size_t)chunk * NH_ + (size_t)(n * H_ + h)) * D_ + tid] = s;
  }
}

// ---------------- reduce partials -> KV, Ksum ----------------
__global__ __launch_bounds__(256) void reduce_kv(const float* __restrict__ pkv,
                                                 const float* __restrict__ pks,
                                                 float* __restrict__ kvg,
                                                 float* __restrict__ ksg, int C) {
  const int nh = blockIdx.y;
  if (blockIdx.x < 16) {
    const int idx = blockIdx.x * 256 + threadIdx.x;
    float s = 0.f;
    #pragma unroll 1
    for (int c = 0; c < C; ++c)
      s += pkv[((size_t)c * NH_ + nh) * (D_ * E_) + idx];
    kvg[(size_t)nh * (D_ * E_) + idx] = s;
  } else if (threadIdx.x < 64) {
    float s = 0.f;
    #pragma unroll 1
    for (int c = 0; c < C; ++c)
      s += pks[((size_t)c * NH_ + nh) * D_ + threadIdx.x];
    ksg[(size_t)nh * D_ + threadIdx.x] = s;
  }
}

// ---------------- phase 2: out[l][e] = (fQ[l].KV[:,e]) / (fQ[l].Ksum + eps) ---
// grid (L/64, H, N), block 256 (4 waves), wave handles 16 rows.
// Lane (dg=lane>>4, eg=lane&15). Denominator fused; butterfly on VALU
// (permlane swaps) instead of ds_bpermute -> LDS pipe only does q broadcasts.
__global__ __launch_bounds__(256, 4) void p2_out(const float* __restrict__ queries,
                                                 const float* __restrict__ kvg,
                                                 const float* __restrict__ ksg,
                                                 float* __restrict__ out) {
  const int lt = blockIdx.x, h = blockIdx.y, n = blockIdx.z;
  const int tid = threadIdx.x;
  const int wave = tid >> 6, lane = tid & 63;
  const int dg = lane >> 4, eg = lane & 15;
  __shared__ float q_lds[64 * RS_];   // 17408 B

  // KV sub-block: kv[di][ej] = KV[16dg+di][4eg+ej]
  const float* kvb = kvg + (size_t)(n * H_ + h) * (D_ * E_);
  float kv[16][4];
  #pragma unroll
  for (int i = 0; i < 16; ++i) {
    float4 t4 = *(const float4*)&kvb[(unsigned)(dg * 16 + i) * E_ + eg * 4];
    kv[i][0] = t4.x; kv[i][1] = t4.y; kv[i][2] = t4.z; kv[i][3] = t4.w;
  }
  float ks[16];
  const float* ksb = ksg + (size_t)(n * H_ + h) * D_ + dg * 16;
  #pragma unroll
  for (int i = 0; i < 16; ++i) ks[i] = ksb[i];

  // stage fQ tile [64][64] (elu applied), coalesced float4: 16 rows/pass
  const float* qb = queries + ((size_t)(n * L_ + lt * 64) * H_ + h) * D_;
  {
    const int srow = tid >> 4, scol = (tid & 15) * 4;
    #pragma unroll
    for (int p = 0; p < 4; ++p) {
      const int r = p * 16 + srow;
      float4 q4 = *(const float4*)(qb + (unsigned)r * HD_ + scol);
      float4 f;
      f.x = elu1(q4.x); f.y = elu1(q4.y); f.z = elu1(q4.z); f.w = elu1(q4.w);
      *(float4*)&q_lds[r * RS_ + scol] = f;
    }
  }
  __syncthreads();

  float* ob = out + ((size_t)(n * L_ + lt * 64) * H_ + h) * E_;
  float4 o4 = make_float4(0.f, 0.f, 0.f, 0.f);
  #pragma unroll 4
  for (int rr = 0; rr < 16; ++rr) {
    const int r = wave * 16 + rr;
    const float* qr = &q_lds[r * RS_ + dg * 16];
    float4 q0 = *(const float4*)(qr + 0);
    float4 q1 = *(const float4*)(qr + 4);
    float4 q2 = *(const float4*)(qr + 8);
    float4 q3 = *(const float4*)(qr + 12);
    float a0 = 0.f, a1 = 0.f, a2 = 0.f, a3 = 0.f, dn = 0.f;
    #define P2ACC(qc, i)                      \
      a0 = fmaf(qc, kv[i][0], a0);            \
      a1 = fmaf(qc, kv[i][1], a1);            \
      a2 = fmaf(qc, kv[i][2], a2);            \
      a3 = fmaf(qc, kv[i][3], a3);            \
      dn = fmaf(qc, ks[i], dn);
    P2ACC(q0.x, 0)  P2ACC(q0.y, 1)  P2ACC(q0.z, 2)  P2ACC(q0.w, 3)
    P2ACC(q1.x, 4)  P2ACC(q1.y, 5)  P2ACC(q1.z, 6)  P2ACC(q1.w, 7)
    P2ACC(q2.x, 8)  P2ACC(q2.y, 9)  P2ACC(q2.z, 10) P2ACC(q2.w, 11)
    P2ACC(q3.x, 12) P2ACC(q3.y, 13) P2ACC(q3.z, 14) P2ACC(q3.w, 15)
    #undef P2ACC
    a0 = red32(red16(a0));
    a1 = red32(red16(a1));
    a2 = red32(red16(a2));
    a3 = red32(red16(a3));
    dn = red32(red16(dn));
#if __has_builtin(__builtin_amdgcn_rcpf)
    float z = __builtin_amdgcn_rcpf(dn + EPS_);
#else
    float z = 1.0f / (dn + EPS_);
#endif
    if (dg == (rr & 3)) { o4.x = a0 * z; o4.y = a1 * z; o4.z = a2 * z; o4.w = a3 * z; }
    if ((rr & 3) == 3) {   // full-wave 1 KiB store: lane (dg,eg) -> row base+dg
      const int rb = wave * 16 + (rr & ~3) + dg;
      *(float4*)(ob + (unsigned)rb * (H_ * E_) + eg * 4) = o4;
    }
  }
}

extern "C" void kernel_launch(void* const* d_in, const int* in_sizes, int n_in,
                              void* d_out, int out_size, void* d_ws, size_t ws_size,
                              hipStream_t stream) {
  const float* q = (const float*)d_in[0];
  const float* k = (const float*)d_in[1];
  const float* v = (const float*)d_in[2];
  float* outp = (float*)d_out;

  float* kvg = (float*)d_ws;                         // NH * 4096
  float* ksg = kvg + (size_t)NH_ * D_ * E_;          // NH * 64
  float* pkv = ksg + (size_t)NH_ * D_;               // C * NH * 4096
  int C = 32;
  while (C > 1) {
    size_t need = ((size_t)NH_ * D_ * E_ + (size_t)NH_ * D_ +
                   (size_t)C * NH_ * (D_ * E_ + D_)) * sizeof(float);
    if (need <= ws_size) break;
    C >>= 1;
  }
  float* pks = pkv + (size_t)C * NH_ * (D_ * E_);
  const int tiles = S_ / (C * TS_);

  hipLaunchKernelGGL(p1_kv, dim3(C, H_, N_), dim3(512), 0, stream, k, v, pkv, pks, tiles);
  hipLaunchKernelGGL(reduce_kv, dim3(17, NH_), dim3(256), 0, stream, pkv, pks, kvg, ksg, C);
  hipLaunchKernelGGL(p2_out, dim3(L_ / 64, H_, N_), dim3(256), 0, stream, q, kvg, ksg, outp);
}